// Round 7
// baseline (180.611 us; speedup 1.0000x reference)
//
#include <hip/hip_runtime.h>
#include <hip/hip_cooperative_groups.h>

// out[b] = SCALE * dot(x[b], sum_g wsums[g]),  SCALE = 1.5 * 0.5 = 0.75
// x: [1024, 8192] fp32 (streamed once), wsums: [32, 8192] fp32, out: [1024] fp32
//
// R10 = R8/R9 resubmit (both benches failed on GPU acquisition; never measured).
// Single COOPERATIVE launch. R7 (2-kernel fused) measured 75.26 us, absmax 0.0;
// rocprof top-5 = harness fillBuffer resets only (43.5 us 256 MiB ws poison
// @77% HBM peak + x/wsums restores). Our dispatches are invisible (<43 us) --
// est. fused ~6-7 us + reduce ~2 us + 2 dispatch gaps. Only controllable
// slack left is launch structure: fold the 8->1 partial reduce into the SAME
// kernel behind a grid-wide sync, eliminating the reduce dispatch + gap.
//   grid = 512 blocks (2/CU, trivially co-resident -> cooperative legal).
//   Phase 1: fold chunk of sum_g wsums[g] into LDS (chunk = blockIdx & 7,
//            XCD-affine under round-robin -> wsums HBM-fetched once).
//   Phase 2: 16 rows/block x 16 threads/row float4 dot vs LDS; 16-lane
//            shuffle reduce -> partial[row][chunk] (one writer, determ.).
//   threadfence (device scope) + grid.sync() -> blocks 0-3 sum 8 partials/row
//   (fence+grid-sync = release/acquire across XCD L2s, G16-safe).
// Fallback: if hipLaunchCooperativeKernel is rejected, launch the proven
// 2-kernel R7 path (same bodies) -- experiment is safe either way.
// Decision rule next bench: <=74 us -> confirmed (then likely ROOFLINE);
// >=75.5 us -> grid-sync costs more than saved dispatch, revert to R7.
// NOTE R3 (kept): nontemporal loads on x regressed; x single-pass, plain loads.
// Floor: 33 MiB HBM ~= 5.3 us + launch; harness reset (~49 us fills) dominates.

#define K_DIM 8192
#define G_DIM 32
#define SCALE 0.75f
#define NCHUNK 8
#define CHUNK (K_DIM / NCHUNK)   // 1024 floats per chunk
#define CHUNK4 (CHUNK / 4)       // 256 float4 per chunk
#define ROWS_PER 16              // rows per block
#define THREADS 256

namespace cg = cooperative_groups;

typedef float floatx4 __attribute__((ext_vector_type(4)));

// Shared device body: fold + row-dot -> partial[row][chunk].
__device__ __forceinline__ void fused_body(
    const float* __restrict__ x, const float* __restrict__ wsums,
    float* __restrict__ partial) {
    const int bi     = blockIdx.x;
    const int chunk  = bi & (NCHUNK - 1);  // low bits -> XCD-affine chunk sharing
    const int rowgrp = bi >> 3;
    const int t      = threadIdx.x;

    __shared__ floatx4 w4[CHUNK4];         // 4 KiB folded w chunk

    // Phase 1: w_chunk[j] = sum_g wsums[g][chunk*1024 + j]; one float4/thread.
    {
        const floatx4* ws4 =
            reinterpret_cast<const floatx4*>(wsums) + chunk * CHUNK4 + t;
        floatx4 acc = ws4[0];
#pragma unroll
        for (int g = 1; g < G_DIM; ++g)
            acc += ws4[(size_t)g * (K_DIM / 4)];
        w4[t] = acc;
    }
    __syncthreads();

    // Phase 2: 16 threads per row; each thread 16 float4 of x vs LDS w.
    const int rlane = t & 15;
    const int row   = rowgrp * ROWS_PER + (t >> 4);
    const floatx4* xr4 = reinterpret_cast<const floatx4*>(x) +
                         (size_t)row * (K_DIM / 4) + chunk * CHUNK4 + rlane;
    float acc = 0.f;
#pragma unroll
    for (int i = 0; i < CHUNK4 / 16; ++i) {   // 16 iterations
        const floatx4 xv = xr4[i * 16];
        const floatx4 wv = w4[rlane + i * 16];
        acc += xv.x * wv.x + xv.y * wv.y + xv.z * wv.z + xv.w * wv.w;
    }

    // Reduce across the 16 lanes of this row (xor masks < 16 stay in-group).
#pragma unroll
    for (int off = 8; off > 0; off >>= 1)
        acc += __shfl_xor(acc, off, 64);

    if (rlane == 0) partial[row * NCHUNK + chunk] = acc;
}

__device__ __forceinline__ void reduce_body(
    const float* __restrict__ partial, float* __restrict__ out, int b) {
    const floatx4* p4 = reinterpret_cast<const floatx4*>(partial) + b * 2;
    const floatx4 a = p4[0];
    const floatx4 c = p4[1];
    out[b] = (a.x + a.y + a.z + a.w + c.x + c.y + c.z + c.w) * SCALE;
}

// Single cooperative kernel: fused body, grid sync, blocks 0-3 reduce.
__global__ void __launch_bounds__(THREADS) fused_coop_kernel(
    const float* __restrict__ x, const float* __restrict__ wsums,
    float* __restrict__ partial, float* __restrict__ out) {
    fused_body(x, wsums, partial);
    __threadfence();               // device-scope release of partial writes
    cg::this_grid().sync();        // all 512 blocks co-resident (2/CU)
    if (blockIdx.x < 4) {
        const int b = blockIdx.x * THREADS + threadIdx.x;  // 0..1023
        reduce_body(partial, out, b);
    }
}

// Fallback pair (R7-proven path), used only if cooperative launch is rejected.
__global__ void __launch_bounds__(THREADS) fused_partial_kernel(
    const float* __restrict__ x, const float* __restrict__ wsums,
    float* __restrict__ partial) {
    fused_body(x, wsums, partial);
}

__global__ void __launch_bounds__(256) reduce_kernel(
    const float* __restrict__ partial, float* __restrict__ out) {
    reduce_body(partial, out, blockIdx.x * 256 + threadIdx.x);
}

extern "C" void kernel_launch(void* const* d_in, const int* in_sizes, int n_in,
                              void* d_out, int out_size, void* d_ws, size_t ws_size,
                              hipStream_t stream) {
    const float* x     = (const float*)d_in[0];   // [1024, 8192]
    const float* wsums = (const float*)d_in[1];   // [32, 8192]
    float* out         = (float*)d_out;           // [1024]
    float* partial     = (float*)d_ws;            // [1024][8] floats = 32 KiB

    const int n_rows = in_sizes[0] / K_DIM;       // 1024
    const int n_blocks = NCHUNK * (n_rows / ROWS_PER);  // 512

    void* args[] = {(void*)&x, (void*)&wsums, (void*)&partial, (void*)&out};
    hipError_t err = hipLaunchCooperativeKernel(
        (const void*)fused_coop_kernel, dim3(n_blocks), dim3(THREADS),
        args, 0, stream);
    if (err != hipSuccess) {
        // Safe fallback: proven 2-kernel path (R7, measured 75.26 us).
        fused_partial_kernel<<<n_blocks, THREADS, 0, stream>>>(x, wsums, partial);
        reduce_kernel<<<n_rows / 256, 256, 0, stream>>>(partial, out);
    }
}